// Round 9
// baseline (242.189 us; speedup 1.0000x reference)
//
#include <hip/hip_runtime.h>
#include <stdint.h>

#define BATCH 2
#define SEQ   1024
#define DIM_  1024
#define DS_   16
#define DI_   2048
#define NTOK  (BATCH*SEQ)   // 2048
#define NSEG  32
#define LSEG  (SEQ/NSEG)    // 32

typedef unsigned short u16;
using s16x8 = __attribute__((ext_vector_type(8))) short;
using f32x4 = __attribute__((ext_vector_type(4))) float;
using u16x4 = __attribute__((ext_vector_type(4))) unsigned short;
using u16x8 = __attribute__((ext_vector_type(8))) unsigned short;

__device__ __forceinline__ float bf2f(u16 u) {
  union { unsigned int i; float f; } c; c.i = ((unsigned int)u) << 16; return c.f;
}
__device__ __forceinline__ u16 f2bf(float f) {
  union { float f; unsigned int i; } c; c.f = f;
  unsigned int r = c.i + 0x7fffu + ((c.i >> 16) & 1u);
  return (u16)(r >> 16);
}
__device__ __forceinline__ float softplus_f(float x) {
  return (x > 15.f) ? x : __logf(1.f + __expf(x));
}

// x_proj_w (33,2048) f32 -> (64,2048) bf16 zero-padded
__global__ __launch_bounds__(256) void cvt_pad_kernel(const float* __restrict__ a,
    u16* __restrict__ o) {
  int i = blockIdx.x * 256 + threadIdx.x;
  if (i >= 32768) return;
  int p = (i * 4) >> 11;
  u16x4 r;
  if (p < 33) {
    float4 v = ((const float4*)a)[i];
    r[0] = f2bf(v.x); r[1] = f2bf(v.y); r[2] = f2bf(v.z); r[3] = f2bf(v.w);
  } else {
    r[0] = 0; r[1] = 0; r[2] = 0; r[3] = 0;
  }
  ((u16x4*)o)[i] = r;
}

// ---------------- LayerNorm ----------------
__global__ __launch_bounds__(256) void ln_kernel(const float* __restrict__ x,
    const float* __restrict__ w, const float* __restrict__ b, u16* __restrict__ xn) {
  int t = blockIdx.x, tid = threadIdx.x;
  const float* row = x + (size_t)t * DIM_;
  float4 v = ((const float4*)row)[tid];
  float f[4] = {v.x, v.y, v.z, v.w};
  float s = 0.f, sq = 0.f;
#pragma unroll
  for (int j = 0; j < 4; j++) { s += f[j]; sq += f[j] * f[j]; }
#pragma unroll
  for (int m = 1; m < 64; m <<= 1) { s += __shfl_xor(s, m); sq += __shfl_xor(sq, m); }
  __shared__ float rs_[4], rq_[4];
  int wv = tid >> 6;
  if ((tid & 63) == 0) { rs_[wv] = s; rq_[wv] = sq; }
  __syncthreads();
  s = rs_[0] + rs_[1] + rs_[2] + rs_[3];
  sq = rq_[0] + rq_[1] + rq_[2] + rq_[3];
  float mu = s * (1.0f / DIM_);
  float var = sq * (1.0f / DIM_) - mu * mu;
  float rstd = rsqrtf(var + 1e-5f);
  float4 wn = ((const float4*)w)[tid];
  float4 bn = ((const float4*)b)[tid];
  u16x4 o;
  o[0] = f2bf((f[0] - mu) * rstd * wn.x + bn.x);
  o[1] = f2bf((f[1] - mu) * rstd * wn.y + bn.y);
  o[2] = f2bf((f[2] - mu) * rstd * wn.z + bn.z);
  o[3] = f2bf((f[3] - mu) * rstd * wn.w + bn.w);
  *(u16x4*)(xn + (size_t)t * DIM_ + tid * 4) = o;
}

// ---------------- GEMM C = A(M,K)bf16 * W(N,K)^T, f32 acc ----------------
// SWZ: XCD-aware blockIdx.x remap (gridX must be divisible by 8)
template<int TBM, int TBN, int BK, typename OUT, int EPI, int WF32, int KSPLIT = 1, int SWZ = 0>
__global__ __launch_bounds__(256) void gemm_bt(const u16* __restrict__ A,
    const void* __restrict__ Wt_, OUT* __restrict__ C, const float* __restrict__ X,
    int M, int N, int K) {
  constexpr int LDT = BK + 8;
  constexpr int TPR = BK / 8;
  constexpr int RPP = 256 / TPR;
  constexpr int ALn = TBM / RPP;
  constexpr int BLn = TBN / RPP;
  constexpr int KK = BK / 32;
  constexpr int WM = TBM / 2, WN = TBN / 2;
  constexpr int MI = WM / 16, NJ = WN / 16;
  __shared__ __align__(16) u16 sA[TBM * LDT];
  __shared__ __align__(16) u16 sB[TBN * LDT];
  const int tid = threadIdx.x;
  const int lane = tid & 63, wv = tid >> 6;
  const int wm = (wv >> 1) * WM, wn = (wv & 1) * WN;
  const int bxl = SWZ ? ((blockIdx.x & 7) * (gridDim.x >> 3) + (blockIdx.x >> 3))
                      : blockIdx.x;
  const int bm0 = blockIdx.y * TBM, bn0 = bxl * TBN;
  const int q = lane >> 4, r16 = lane & 15;
  const int srow = tid / TPR, scol = (tid % TPR) * 8;
  const int kc = K / KSPLIT;
  const int k0 = (KSPLIT > 1) ? blockIdx.z * kc : 0;
  const int kend = k0 + kc;

  f32x4 acc[MI][NJ];
#pragma unroll
  for (int i = 0; i < MI; i++)
#pragma unroll
    for (int j = 0; j < NJ; j++)
#pragma unroll
      for (int r = 0; r < 4; r++) acc[i][j][r] = 0.f;

  const u16* Ag = A + (size_t)bm0 * K + scol + k0;
  const u16* Wgh = (const u16*)Wt_ + (size_t)bn0 * K + scol + k0;
  const float* Wgf = (const float*)Wt_ + (size_t)bn0 * K + scol + k0;
  s16x8 ra[ALn], rb[BLn];
  float4 rbf[BLn][2];
#pragma unroll
  for (int i = 0; i < ALn; i++) ra[i] = *(const s16x8*)(Ag + (size_t)(srow + i * RPP) * K);
  if constexpr (WF32) {
#pragma unroll
    for (int i = 0; i < BLn; i++) {
      const float* p = Wgf + (size_t)(srow + i * RPP) * K;
      rbf[i][0] = *(const float4*)p;
      rbf[i][1] = *(const float4*)(p + 4);
    }
  } else {
#pragma unroll
    for (int i = 0; i < BLn; i++) rb[i] = *(const s16x8*)(Wgh + (size_t)(srow + i * RPP) * K);
  }

  for (int kt = k0; kt < kend; kt += BK) {
    __syncthreads();
#pragma unroll
    for (int i = 0; i < ALn; i++) *(s16x8*)&sA[(srow + i * RPP) * LDT + scol] = ra[i];
    if constexpr (WF32) {
#pragma unroll
      for (int i = 0; i < BLn; i++) {
        u16x8 wb;
        wb[0] = f2bf(rbf[i][0].x); wb[1] = f2bf(rbf[i][0].y);
        wb[2] = f2bf(rbf[i][0].z); wb[3] = f2bf(rbf[i][0].w);
        wb[4] = f2bf(rbf[i][1].x); wb[5] = f2bf(rbf[i][1].y);
        wb[6] = f2bf(rbf[i][1].z); wb[7] = f2bf(rbf[i][1].w);
        *(u16x8*)&sB[(srow + i * RPP) * LDT + scol] = wb;
      }
    } else {
#pragma unroll
      for (int i = 0; i < BLn; i++) *(s16x8*)&sB[(srow + i * RPP) * LDT + scol] = rb[i];
    }
    __syncthreads();
    int kn = kt + BK - k0;
    if (kn < kc) {
#pragma unroll
      for (int i = 0; i < ALn; i++) ra[i] = *(const s16x8*)(Ag + (size_t)(srow + i * RPP) * K + kn);
      if constexpr (WF32) {
#pragma unroll
        for (int i = 0; i < BLn; i++) {
          const float* p = Wgf + (size_t)(srow + i * RPP) * K + kn;
          rbf[i][0] = *(const float4*)p;
          rbf[i][1] = *(const float4*)(p + 4);
        }
      } else {
#pragma unroll
        for (int i = 0; i < BLn; i++) rb[i] = *(const s16x8*)(Wgh + (size_t)(srow + i * RPP) * K + kn);
      }
    }
#pragma unroll
    for (int kk = 0; kk < KK; kk++) {
      s16x8 fa[MI], fb[NJ];
#pragma unroll
      for (int i = 0; i < MI; i++)
        fa[i] = *(const s16x8*)&sA[(wm + i * 16 + r16) * LDT + kk * 32 + q * 8];
#pragma unroll
      for (int j = 0; j < NJ; j++)
        fb[j] = *(const s16x8*)&sB[(wn + j * 16 + r16) * LDT + kk * 32 + q * 8];
#pragma unroll
      for (int i = 0; i < MI; i++)
#pragma unroll
        for (int j = 0; j < NJ; j++)
          acc[i][j] = __builtin_amdgcn_mfma_f32_16x16x32_bf16(fa[i], fb[j], acc[i][j], 0, 0, 0);
    }
  }
  OUT* Cz = C + ((KSPLIT > 1) ? (size_t)blockIdx.z * M * N : 0);
#pragma unroll
  for (int i = 0; i < MI; i++)
#pragma unroll
    for (int j = 0; j < NJ; j++) {
      int row0 = bm0 + wm + i * 16 + q * 4;
      int col = bn0 + wn + j * 16 + r16;
#pragma unroll
      for (int r = 0; r < 4; r++) {
        size_t off = (size_t)(row0 + r) * N + col;
        float v = acc[i][j][r];
        if constexpr (EPI == 1) v += X[off];
        if constexpr (sizeof(OUT) == 2) Cz[off] = f2bf(v);
        else                            Cz[off] = v;
      }
    }
}

__global__ __launch_bounds__(256) void reduce_out_kernel(const float* __restrict__ part,
    const float* __restrict__ x, float* __restrict__ out) {
  int g = blockIdx.x * 256 + threadIdx.x;   // over NTOK*DIM_/4
  constexpr size_t STR = (size_t)NTOK * DIM_ / 4;
  float4 a = ((const float4*)part)[g];
  float4 b = ((const float4*)part)[g + STR];
  float4 xv = ((const float4*)x)[g];
  float4 o;
  o.x = xv.x + a.x + b.x;
  o.y = xv.y + a.y + b.y;
  o.z = xv.z + a.z + b.z;
  o.w = xv.w + a.w + b.w;
  ((float4*)out)[g] = o;
}

// ---------------- depthwise causal conv (DC=4) + silu ----------------
__global__ __launch_bounds__(256) void conv_silu_kernel(const u16* __restrict__ xz,
    const float* __restrict__ cw, const float* __restrict__ cb, u16* __restrict__ xc) {
  int t = blockIdx.x;
  int l = t & (SEQ - 1);
  int c0 = threadIdx.x * 8;
  float acc[8], wk[8][4];
#pragma unroll
  for (int j = 0; j < 8; j++) {
    float4 wv = ((const float4*)cw)[c0 + j];
    wk[j][0] = wv.x; wk[j][1] = wv.y; wk[j][2] = wv.z; wk[j][3] = wv.w;
    acc[j] = cb[c0 + j];
  }
#pragma unroll
  for (int k = 0; k < 4; k++) {
    int lk = l - 3 + k;
    if (lk >= 0) {
      u16x8 v = *(const u16x8*)(xz + (size_t)(t - 3 + k) * (2 * DI_) + c0);
#pragma unroll
      for (int j = 0; j < 8; j++) acc[j] = fmaf(bf2f(v[j]), wk[j][k], acc[j]);
    }
  }
  u16x8 o;
#pragma unroll
  for (int j = 0; j < 8; j++) {
    float a = acc[j];
    o[j] = f2bf(a / (1.0f + __expf(-a)));
  }
  *(u16x8*)(xc + (size_t)t * DI_ + c0) = o;
}

// ---------------- fused: split-K reduce of xproj + delta(softplus) + B/C repack ----------------
// part: 8 x (NTOK x 64) f32. delta -> xi-half of xz (stride 2*DI_). bc[t][0..31] = xp cols 1..32.
__global__ __launch_bounds__(256) void xp_finish_kernel(const float* __restrict__ part,
    const float* __restrict__ dtw, const float* __restrict__ dtb,
    u16* __restrict__ xz, float* __restrict__ bc) {
  int t = blockIdx.x;
  int tid = threadIdx.x;
  __shared__ float xps[64];
  if (tid < 64) {
    float s = 0.f;
#pragma unroll
    for (int k = 0; k < 8; k++)
      s += part[(size_t)k * NTOK * 64 + (size_t)t * 64 + tid];
    xps[tid] = s;
  }
  __syncthreads();
  if (tid < 32) bc[(size_t)t * 32 + tid] = xps[1 + tid];
  float dr = xps[0];
  int c0 = tid * 8;
  float wv[8], bv[8];
  *(float4*)wv = ((const float4*)(dtw + c0))[0];
  *(float4*)(wv + 4) = ((const float4*)(dtw + c0))[1];
  *(float4*)bv = ((const float4*)(dtb + c0))[0];
  *(float4*)(bv + 4) = ((const float4*)(dtb + c0))[1];
  u16x8 o;
#pragma unroll
  for (int j = 0; j < 8; j++) o[j] = f2bf(softplus_f(dr * wv[j] + bv[j]));
  *(u16x8*)(xz + (size_t)t * (2 * DI_) + c0) = o;
}

// ============ segmented selective scan (4 states/lane) ============
__global__ __launch_bounds__(256) void scan_pass1(const float* __restrict__ bc,
    const u16* __restrict__ dlt, const u16* __restrict__ xc,
    const float* __restrict__ A_log, float* __restrict__ P, float* __restrict__ Q) {
  int tid = threadIdx.x;
  int lane = tid & 63, wv = tid >> 6;
  int nl = (lane & 3) * 4;
  int d = blockIdx.x * 64 + wv * 16 + (lane >> 2);
  int s = blockIdx.y, b = blockIdx.z;
  int t0 = b * SEQ + s * LSEG;
  float4 Ain = *(const float4*)(A_log + d * DS_ + nl);
  f32x4 Av;
  Av[0] = -__expf(Ain.x); Av[1] = -__expf(Ain.y);
  Av[2] = -__expf(Ain.z); Av[3] = -__expf(Ain.w);
  f32x4 Pv, h;
#pragma unroll
  for (int i = 0; i < 4; i++) { Pv[i] = 1.f; h[i] = 0.f; }
#pragma unroll 4
  for (int j = 0; j < LSEG; j++) {
    int t = t0 + j;
    float delta = bf2f(dlt[(size_t)t * (2 * DI_) + d]);
    float xcv = bf2f(xc[(size_t)t * DI_ + d]);
    float4 B4 = *(const float4*)(bc + (size_t)t * 32 + nl);
    float du = delta * xcv;
#pragma unroll
    for (int i = 0; i < 4; i++) {
      float a = __expf(delta * Av[i]);
      Pv[i] *= a;
      float bi = (i == 0) ? B4.x : (i == 1) ? B4.y : (i == 2) ? B4.z : B4.w;
      h[i] = fmaf(a, h[i], du * bi);
    }
  }
  size_t idx = ((size_t)((b * NSEG + s) * DI_ + d)) * 16 + nl;
  *(f32x4*)(P + idx) = Pv;
  *(f32x4*)(Q + idx) = h;
}

__global__ __launch_bounds__(256) void scan_combine(const float* __restrict__ P,
    float* __restrict__ Q) {
  int g = blockIdx.x * 256 + threadIdx.x;
  int n = g & 15, d = (g >> 4) & (DI_ - 1), b = g >> 15;
  size_t base = ((size_t)b * NSEG * DI_ + d) * 16 + n;
  constexpr size_t STR = (size_t)DI_ * 16;
  float p_[NSEG], q_[NSEG];
#pragma unroll
  for (int s = 0; s < NSEG; s++) {
    p_[s] = P[base + s * STR];
    q_[s] = Q[base + s * STR];
  }
  float hh = 0.f;
#pragma unroll
  for (int s = 0; s < NSEG; s++) {
    Q[base + s * STR] = hh;
    hh = fmaf(p_[s], hh, q_[s]);
  }
}

// pass2 + fused gate: y = (p + xc*D) * silu(z)
__global__ __launch_bounds__(256) void scan_pass2(const float* __restrict__ bc,
    const u16* __restrict__ dlt, const u16* __restrict__ xc,
    const float* __restrict__ A_log, const float* __restrict__ Dskip,
    const float* __restrict__ Hin, u16* __restrict__ yb) {
  int tid = threadIdx.x;
  int lane = tid & 63, wv = tid >> 6;
  int nl = (lane & 3) * 4;
  int d = blockIdx.x * 64 + wv * 16 + (lane >> 2);
  int s = blockIdx.y, b = blockIdx.z;
  int t0 = b * SEQ + s * LSEG;
  float4 Ain = *(const float4*)(A_log + d * DS_ + nl);
  f32x4 Av;
  Av[0] = -__expf(Ain.x); Av[1] = -__expf(Ain.y);
  Av[2] = -__expf(Ain.z); Av[3] = -__expf(Ain.w);
  float Dv = Dskip[d];
  size_t idx = ((size_t)((b * NSEG + s) * DI_ + d)) * 16 + nl;
  f32x4 h = *(const f32x4*)(Hin + idx);
#pragma unroll 4
  for (int j = 0; j < LSEG; j++) {
    int t = t0 + j;
    float delta = bf2f(dlt[(size_t)t * (2 * DI_) + d]);
    float xcv = bf2f(xc[(size_t)t * DI_ + d]);
    float4 B4 = *(const float4*)(bc + (size_t)t * 32 + nl);
    float4 C4 = *(const float4*)(bc + (size_t)t * 32 + 16 + nl);
    float du = delta * xcv;
#pragma unroll
    for (int i = 0; i < 4; i++) {
      float a = __expf(delta * Av[i]);
      float bi = (i == 0) ? B4.x : (i == 1) ? B4.y : (i == 2) ? B4.z : B4.w;
      h[i] = fmaf(a, h[i], du * bi);
    }
    float p = h[0] * C4.x;
    p = fmaf(h[1], C4.y, p);
    p = fmaf(h[2], C4.z, p);
    p = fmaf(h[3], C4.w, p);
    p += __shfl_xor(p, 1);
    p += __shfl_xor(p, 2);
    if ((lane & 3) == 0) {
      float z = bf2f(dlt[(size_t)t * (2 * DI_) + DI_ + d]);  // z-half of xz
      float sz = z / (1.0f + __expf(-z));
      yb[(size_t)t * DI_ + d] = f2bf((p + xcv * Dv) * sz);
    }
  }
}

extern "C" void kernel_launch(void* const* d_in, const int* in_sizes, int n_in,
                              void* d_out, int out_size, void* d_ws, size_t ws_size,
                              hipStream_t stream) {
  const float* x      = (const float*)d_in[0];
  const float* norm_w = (const float*)d_in[1];
  const float* norm_b = (const float*)d_in[2];
  const float* in_w   = (const float*)d_in[3];
  const float* conv_w = (const float*)d_in[4];
  const float* conv_b = (const float*)d_in[5];
  const float* xproj_w= (const float*)d_in[6];
  const float* dt_w   = (const float*)d_in[7];
  const float* dt_b   = (const float*)d_in[8];
  const float* A_log  = (const float*)d_in[9];
  const float* D_skip = (const float*)d_in[10];
  const float* out_w  = (const float*)d_in[11];
  float* out = (float*)d_out;

  char* ws = (char*)d_ws;
  size_t off = 0;
  auto alloc = [&](size_t bytes) { void* p = ws + off; off += (bytes + 255) & ~255ULL; return p; };
  u16* xpw_bf = (u16*)alloc((size_t)64 * DI_ * 2);
  u16* xz     = (u16*)alloc((size_t)NTOK * 2 * DI_ * 2);    // 16.78 MB
  u16* xc     = (u16*)alloc((size_t)NTOK * DI_ * 2);
  float* bc   = (float*)alloc((size_t)NTOK * 32 * 4);
  char* regionA = (char*)alloc((size_t)BATCH * NSEG * DI_ * 16 * 4);  // 8.4 MB
  float* Q = (float*)alloc((size_t)BATCH * NSEG * DI_ * 16 * 4);      // 8.4 MB
  u16* xn   = (u16*)regionA;
  float* P  = (float*)regionA;
  u16* yb   = (u16*)regionA;
  float* xp_part = Q;              // 4 MB, dead before pass1 writes Q
  float* out_part = (float*)xz;    // 16.78 MB, xz fully dead after pass2 (gate fused)
  // total ~33.3 MB (proven safe rounds 3-8)

  cvt_pad_kernel<<<128, 256, 0, stream>>>(xproj_w, xpw_bf);
  ln_kernel<<<NTOK, 256, 0, stream>>>(x, norm_w, norm_b, xn);
  // in_proj: 128x64, BK=64, XCD-swizzled -> 1024 blocks (4/CU)
  gemm_bt<128, 64, 64, u16, 0, 1, 1, 1><<<dim3((2 * DI_) / 64, NTOK / 128), 256, 0, stream>>>(
      xn, in_w, xz, nullptr, NTOK, 2 * DI_, DIM_);
  conv_silu_kernel<<<NTOK, 256, 0, stream>>>(xz, conv_w, conv_b, xc);
  // x_proj: split-K=8, BK=32 -> 256 blocks
  gemm_bt<64, 64, 32, float, 0, 0, 8><<<dim3(1, NTOK / 64, 8), 256, 0, stream>>>(
      xc, xpw_bf, xp_part, nullptr, NTOK, 64, DI_);
  // fused reduce + delta + bc
  xp_finish_kernel<<<NTOK, 256, 0, stream>>>(xp_part, dt_w, dt_b, xz, bc);
  scan_pass1<<<dim3(DI_ / 64, NSEG, BATCH), 256, 0, stream>>>(bc, xz, xc, A_log, P, Q);
  scan_combine<<<BATCH * DI_ * 16 / 256, 256, 0, stream>>>(P, Q);
  scan_pass2<<<dim3(DI_ / 64, NSEG, BATCH), 256, 0, stream>>>(bc, xz, xc, A_log, D_skip,
                                                              Q, yb);
  // out_proj: 64x64, BK=64, split-K=2, XCD-swizzled -> 1024 blocks (4/CU)
  gemm_bt<64, 64, 64, float, 0, 1, 2, 1><<<dim3(DIM_ / 64, NTOK / 64, 2), 256, 0, stream>>>(
      yb, out_w, out_part, nullptr, NTOK, DIM_, DI_);
  reduce_out_kernel<<<NTOK * DIM_ / 4 / 256, 256, 0, stream>>>(out_part, x, out);
}

// Round 10
// 241.655 us; speedup vs baseline: 1.0022x; 1.0022x over previous
//
#include <hip/hip_runtime.h>
#include <stdint.h>

#define BATCH 2
#define SEQ   1024
#define DIM_  1024
#define DS_   16
#define DI_   2048
#define NTOK  (BATCH*SEQ)   // 2048
#define NSEG  32
#define LSEG  (SEQ/NSEG)    // 32

typedef unsigned short u16;
using s16x8 = __attribute__((ext_vector_type(8))) short;
using f32x4 = __attribute__((ext_vector_type(4))) float;
using u16x4 = __attribute__((ext_vector_type(4))) unsigned short;
using u16x8 = __attribute__((ext_vector_type(8))) unsigned short;

__device__ __forceinline__ float bf2f(u16 u) {
  union { unsigned int i; float f; } c; c.i = ((unsigned int)u) << 16; return c.f;
}
__device__ __forceinline__ u16 f2bf(float f) {
  union { float f; unsigned int i; } c; c.f = f;
  unsigned int r = c.i + 0x7fffu + ((c.i >> 16) & 1u);
  return (u16)(r >> 16);
}
__device__ __forceinline__ float softplus_f(float x) {
  return (x > 15.f) ? x : __logf(1.f + __expf(x));
}

// ---------------- f32 -> bf16 streaming convert ----------------
__global__ __launch_bounds__(256) void cvt_kernel(const float* __restrict__ a,
    u16* __restrict__ o, int n4) {
  int i = blockIdx.x * 256 + threadIdx.x;
  if (i >= n4) return;
  float4 v = ((const float4*)a)[i];
  u16x4 r; r[0] = f2bf(v.x); r[1] = f2bf(v.y); r[2] = f2bf(v.z); r[3] = f2bf(v.w);
  ((u16x4*)o)[i] = r;
}

// x_proj_w (33,2048) f32 -> (64,2048) bf16 zero-padded
__global__ __launch_bounds__(256) void cvt_pad_kernel(const float* __restrict__ a,
    u16* __restrict__ o) {
  int i = blockIdx.x * 256 + threadIdx.x;
  if (i >= 32768) return;
  int p = (i * 4) >> 11;
  u16x4 r;
  if (p < 33) {
    float4 v = ((const float4*)a)[i];
    r[0] = f2bf(v.x); r[1] = f2bf(v.y); r[2] = f2bf(v.z); r[3] = f2bf(v.w);
  } else {
    r[0] = 0; r[1] = 0; r[2] = 0; r[3] = 0;
  }
  ((u16x4*)o)[i] = r;
}

// ---------------- LayerNorm ----------------
__global__ __launch_bounds__(256) void ln_kernel(const float* __restrict__ x,
    const float* __restrict__ w, const float* __restrict__ b, u16* __restrict__ xn) {
  int t = blockIdx.x, tid = threadIdx.x;
  const float* row = x + (size_t)t * DIM_;
  float4 v = ((const float4*)row)[tid];
  float f[4] = {v.x, v.y, v.z, v.w};
  float s = 0.f, sq = 0.f;
#pragma unroll
  for (int j = 0; j < 4; j++) { s += f[j]; sq += f[j] * f[j]; }
#pragma unroll
  for (int m = 1; m < 64; m <<= 1) { s += __shfl_xor(s, m); sq += __shfl_xor(sq, m); }
  __shared__ float rs_[4], rq_[4];
  int wv = tid >> 6;
  if ((tid & 63) == 0) { rs_[wv] = s; rq_[wv] = sq; }
  __syncthreads();
  s = rs_[0] + rs_[1] + rs_[2] + rs_[3];
  sq = rq_[0] + rq_[1] + rq_[2] + rq_[3];
  float mu = s * (1.0f / DIM_);
  float var = sq * (1.0f / DIM_) - mu * mu;
  float rstd = rsqrtf(var + 1e-5f);
  float4 wn = ((const float4*)w)[tid];
  float4 bn = ((const float4*)b)[tid];
  u16x4 o;
  o[0] = f2bf((f[0] - mu) * rstd * wn.x + bn.x);
  o[1] = f2bf((f[1] - mu) * rstd * wn.y + bn.y);
  o[2] = f2bf((f[2] - mu) * rstd * wn.z + bn.z);
  o[3] = f2bf((f[3] - mu) * rstd * wn.w + bn.w);
  *(u16x4*)(xn + (size_t)t * DIM_ + tid * 4) = o;
}

// ---------------- GEMM C = A(M,K)bf16 * W(N,K)^T bf16, f32 acc ----------------
template<int TBM, int TBN, int BK, typename OUT, int EPI, int KSPLIT = 1, int SWZ = 0>
__global__ __launch_bounds__(256) void gemm_bt(const u16* __restrict__ A,
    const u16* __restrict__ Wt, OUT* __restrict__ C, const float* __restrict__ X,
    int M, int N, int K) {
  constexpr int LDT = BK + 8;
  constexpr int TPR = BK / 8;
  constexpr int RPP = 256 / TPR;
  constexpr int ALn = TBM / RPP;
  constexpr int BLn = TBN / RPP;
  constexpr int KK = BK / 32;
  constexpr int WM = TBM / 2, WN = TBN / 2;
  constexpr int MI = WM / 16, NJ = WN / 16;
  __shared__ __align__(16) u16 sA[TBM * LDT];
  __shared__ __align__(16) u16 sB[TBN * LDT];
  const int tid = threadIdx.x;
  const int lane = tid & 63, wv = tid >> 6;
  const int wm = (wv >> 1) * WM, wn = (wv & 1) * WN;
  const int bxl = SWZ ? ((blockIdx.x & 7) * (gridDim.x >> 3) + (blockIdx.x >> 3))
                      : blockIdx.x;
  const int bm0 = blockIdx.y * TBM, bn0 = bxl * TBN;
  const int q = lane >> 4, r16 = lane & 15;
  const int srow = tid / TPR, scol = (tid % TPR) * 8;
  const int kc = K / KSPLIT;
  const int k0 = (KSPLIT > 1) ? blockIdx.z * kc : 0;
  const int kend = k0 + kc;

  f32x4 acc[MI][NJ];
#pragma unroll
  for (int i = 0; i < MI; i++)
#pragma unroll
    for (int j = 0; j < NJ; j++)
#pragma unroll
      for (int r = 0; r < 4; r++) acc[i][j][r] = 0.f;

  const u16* Ag = A + (size_t)bm0 * K + scol + k0;
  const u16* Wg = Wt + (size_t)bn0 * K + scol + k0;
  s16x8 ra[ALn], rb[BLn];
#pragma unroll
  for (int i = 0; i < ALn; i++) ra[i] = *(const s16x8*)(Ag + (size_t)(srow + i * RPP) * K);
#pragma unroll
  for (int i = 0; i < BLn; i++) rb[i] = *(const s16x8*)(Wg + (size_t)(srow + i * RPP) * K);

  for (int kt = k0; kt < kend; kt += BK) {
    __syncthreads();
#pragma unroll
    for (int i = 0; i < ALn; i++) *(s16x8*)&sA[(srow + i * RPP) * LDT + scol] = ra[i];
#pragma unroll
    for (int i = 0; i < BLn; i++) *(s16x8*)&sB[(srow + i * RPP) * LDT + scol] = rb[i];
    __syncthreads();
    int kn = kt + BK - k0;
    if (kn < kc) {
#pragma unroll
      for (int i = 0; i < ALn; i++) ra[i] = *(const s16x8*)(Ag + (size_t)(srow + i * RPP) * K + kn);
#pragma unroll
      for (int i = 0; i < BLn; i++) rb[i] = *(const s16x8*)(Wg + (size_t)(srow + i * RPP) * K + kn);
    }
#pragma unroll
    for (int kk = 0; kk < KK; kk++) {
      s16x8 fa[MI], fb[NJ];
#pragma unroll
      for (int i = 0; i < MI; i++)
        fa[i] = *(const s16x8*)&sA[(wm + i * 16 + r16) * LDT + kk * 32 + q * 8];
#pragma unroll
      for (int j = 0; j < NJ; j++)
        fb[j] = *(const s16x8*)&sB[(wn + j * 16 + r16) * LDT + kk * 32 + q * 8];
#pragma unroll
      for (int i = 0; i < MI; i++)
#pragma unroll
        for (int j = 0; j < NJ; j++)
          acc[i][j] = __builtin_amdgcn_mfma_f32_16x16x32_bf16(fa[i], fb[j], acc[i][j], 0, 0, 0);
    }
  }
  OUT* Cz = C + ((KSPLIT > 1) ? (size_t)blockIdx.z * M * N : 0);
#pragma unroll
  for (int i = 0; i < MI; i++)
#pragma unroll
    for (int j = 0; j < NJ; j++) {
      int row0 = bm0 + wm + i * 16 + q * 4;
      int col = bn0 + wn + j * 16 + r16;
#pragma unroll
      for (int r = 0; r < 4; r++) {
        size_t off = (size_t)(row0 + r) * N + col;
        float v = acc[i][j][r];
        if constexpr (EPI == 1) v += X[off];
        if constexpr (sizeof(OUT) == 2) Cz[off] = f2bf(v);
        else                            Cz[off] = v;
      }
    }
}

__global__ __launch_bounds__(256) void reduce_out_kernel(const float* __restrict__ part,
    const float* __restrict__ x, float* __restrict__ out) {
  int g = blockIdx.x * 256 + threadIdx.x;
  constexpr size_t STR = (size_t)NTOK * DIM_ / 4;
  float4 a = ((const float4*)part)[g];
  float4 b = ((const float4*)part)[g + STR];
  float4 xv = ((const float4*)x)[g];
  float4 o;
  o.x = xv.x + a.x + b.x;
  o.y = xv.y + a.y + b.y;
  o.z = xv.z + a.z + b.z;
  o.w = xv.w + a.w + b.w;
  ((float4*)out)[g] = o;
}

// ---------------- depthwise causal conv (DC=4) + silu ----------------
__global__ __launch_bounds__(256) void conv_silu_kernel(const u16* __restrict__ xz,
    const float* __restrict__ cw, const float* __restrict__ cb, u16* __restrict__ xc) {
  int t = blockIdx.x;
  int l = t & (SEQ - 1);
  int c0 = threadIdx.x * 8;
  float acc[8], wk[8][4];
#pragma unroll
  for (int j = 0; j < 8; j++) {
    float4 wv = ((const float4*)cw)[c0 + j];
    wk[j][0] = wv.x; wk[j][1] = wv.y; wk[j][2] = wv.z; wk[j][3] = wv.w;
    acc[j] = cb[c0 + j];
  }
#pragma unroll
  for (int k = 0; k < 4; k++) {
    int lk = l - 3 + k;
    if (lk >= 0) {
      u16x8 v = *(const u16x8*)(xz + (size_t)(t - 3 + k) * (2 * DI_) + c0);
#pragma unroll
      for (int j = 0; j < 8; j++) acc[j] = fmaf(bf2f(v[j]), wk[j][k], acc[j]);
    }
  }
  u16x8 o;
#pragma unroll
  for (int j = 0; j < 8; j++) {
    float a = acc[j];
    o[j] = f2bf(a / (1.0f + __expf(-a)));
  }
  *(u16x8*)(xc + (size_t)t * DI_ + c0) = o;
}

// ---------------- fused: split-K reduce of xproj + delta(softplus) + B/C repack ----------------
__global__ __launch_bounds__(256) void xp_finish_kernel(const float* __restrict__ part,
    const float* __restrict__ dtw, const float* __restrict__ dtb,
    u16* __restrict__ xz, float* __restrict__ bc) {
  int t = blockIdx.x;
  int tid = threadIdx.x;
  __shared__ float xps[64];
  if (tid < 64) {
    float s = 0.f;
#pragma unroll
    for (int k = 0; k < 8; k++)
      s += part[(size_t)k * NTOK * 64 + (size_t)t * 64 + tid];
    xps[tid] = s;
  }
  __syncthreads();
  if (tid < 32) bc[(size_t)t * 32 + tid] = xps[1 + tid];
  float dr = xps[0];
  int c0 = tid * 8;
  float wv[8], bv[8];
  *(float4*)wv = ((const float4*)(dtw + c0))[0];
  *(float4*)(wv + 4) = ((const float4*)(dtw + c0))[1];
  *(float4*)bv = ((const float4*)(dtb + c0))[0];
  *(float4*)(bv + 4) = ((const float4*)(dtb + c0))[1];
  u16x8 o;
#pragma unroll
  for (int j = 0; j < 8; j++) o[j] = f2bf(softplus_f(dr * wv[j] + bv[j]));
  *(u16x8*)(xz + (size_t)t * (2 * DI_) + c0) = o;
}

// ============ segmented selective scan (4 states/lane) ============
__global__ __launch_bounds__(256) void scan_pass1(const float* __restrict__ bc,
    const u16* __restrict__ dlt, const u16* __restrict__ xc,
    const float* __restrict__ A_log, float* __restrict__ P, float* __restrict__ Q) {
  int tid = threadIdx.x;
  int lane = tid & 63, wv = tid >> 6;
  int nl = (lane & 3) * 4;
  int d = blockIdx.x * 64 + wv * 16 + (lane >> 2);
  int s = blockIdx.y, b = blockIdx.z;
  int t0 = b * SEQ + s * LSEG;
  float4 Ain = *(const float4*)(A_log + d * DS_ + nl);
  f32x4 Av;
  Av[0] = -__expf(Ain.x); Av[1] = -__expf(Ain.y);
  Av[2] = -__expf(Ain.z); Av[3] = -__expf(Ain.w);
  f32x4 Pv, h;
#pragma unroll
  for (int i = 0; i < 4; i++) { Pv[i] = 1.f; h[i] = 0.f; }
#pragma unroll 4
  for (int j = 0; j < LSEG; j++) {
    int t = t0 + j;
    float delta = bf2f(dlt[(size_t)t * (2 * DI_) + d]);
    float xcv = bf2f(xc[(size_t)t * DI_ + d]);
    float4 B4 = *(const float4*)(bc + (size_t)t * 32 + nl);
    float du = delta * xcv;
#pragma unroll
    for (int i = 0; i < 4; i++) {
      float a = __expf(delta * Av[i]);
      Pv[i] *= a;
      float bi = (i == 0) ? B4.x : (i == 1) ? B4.y : (i == 2) ? B4.z : B4.w;
      h[i] = fmaf(a, h[i], du * bi);
    }
  }
  size_t idx = ((size_t)((b * NSEG + s) * DI_ + d)) * 16 + nl;
  *(f32x4*)(P + idx) = Pv;
  *(f32x4*)(Q + idx) = h;
}

__global__ __launch_bounds__(256) void scan_combine(const float* __restrict__ P,
    float* __restrict__ Q) {
  int g = blockIdx.x * 256 + threadIdx.x;
  int n = g & 15, d = (g >> 4) & (DI_ - 1), b = g >> 15;
  size_t base = ((size_t)b * NSEG * DI_ + d) * 16 + n;
  constexpr size_t STR = (size_t)DI_ * 16;
  float p_[NSEG], q_[NSEG];
#pragma unroll
  for (int s = 0; s < NSEG; s++) {
    p_[s] = P[base + s * STR];
    q_[s] = Q[base + s * STR];
  }
  float hh = 0.f;
#pragma unroll
  for (int s = 0; s < NSEG; s++) {
    Q[base + s * STR] = hh;
    hh = fmaf(p_[s], hh, q_[s]);
  }
}

// pass2 + fused gate: y = (p + xc*D) * silu(z)
__global__ __launch_bounds__(256) void scan_pass2(const float* __restrict__ bc,
    const u16* __restrict__ dlt, const u16* __restrict__ xc,
    const float* __restrict__ A_log, const float* __restrict__ Dskip,
    const float* __restrict__ Hin, u16* __restrict__ yb) {
  int tid = threadIdx.x;
  int lane = tid & 63, wv = tid >> 6;
  int nl = (lane & 3) * 4;
  int d = blockIdx.x * 64 + wv * 16 + (lane >> 2);
  int s = blockIdx.y, b = blockIdx.z;
  int t0 = b * SEQ + s * LSEG;
  float4 Ain = *(const float4*)(A_log + d * DS_ + nl);
  f32x4 Av;
  Av[0] = -__expf(Ain.x); Av[1] = -__expf(Ain.y);
  Av[2] = -__expf(Ain.z); Av[3] = -__expf(Ain.w);
  float Dv = Dskip[d];
  size_t idx = ((size_t)((b * NSEG + s) * DI_ + d)) * 16 + nl;
  f32x4 h = *(const f32x4*)(Hin + idx);
#pragma unroll 4
  for (int j = 0; j < LSEG; j++) {
    int t = t0 + j;
    float delta = bf2f(dlt[(size_t)t * (2 * DI_) + d]);
    float xcv = bf2f(xc[(size_t)t * DI_ + d]);
    float4 B4 = *(const float4*)(bc + (size_t)t * 32 + nl);
    float4 C4 = *(const float4*)(bc + (size_t)t * 32 + 16 + nl);
    float du = delta * xcv;
#pragma unroll
    for (int i = 0; i < 4; i++) {
      float a = __expf(delta * Av[i]);
      float bi = (i == 0) ? B4.x : (i == 1) ? B4.y : (i == 2) ? B4.z : B4.w;
      h[i] = fmaf(a, h[i], du * bi);
    }
    float p = h[0] * C4.x;
    p = fmaf(h[1], C4.y, p);
    p = fmaf(h[2], C4.z, p);
    p = fmaf(h[3], C4.w, p);
    p += __shfl_xor(p, 1);
    p += __shfl_xor(p, 2);
    if ((lane & 3) == 0) {
      float z = bf2f(dlt[(size_t)t * (2 * DI_) + DI_ + d]);
      float sz = z / (1.0f + __expf(-z));
      yb[(size_t)t * DI_ + d] = f2bf((p + xcv * Dv) * sz);
    }
  }
}

extern "C" void kernel_launch(void* const* d_in, const int* in_sizes, int n_in,
                              void* d_out, int out_size, void* d_ws, size_t ws_size,
                              hipStream_t stream) {
  const float* x      = (const float*)d_in[0];
  const float* norm_w = (const float*)d_in[1];
  const float* norm_b = (const float*)d_in[2];
  const float* in_w   = (const float*)d_in[3];
  const float* conv_w = (const float*)d_in[4];
  const float* conv_b = (const float*)d_in[5];
  const float* xproj_w= (const float*)d_in[6];
  const float* dt_w   = (const float*)d_in[7];
  const float* dt_b   = (const float*)d_in[8];
  const float* A_log  = (const float*)d_in[9];
  const float* D_skip = (const float*)d_in[10];
  const float* out_w  = (const float*)d_in[11];
  float* out = (float*)d_out;

  char* ws = (char*)d_ws;
  size_t off = 0;
  auto alloc = [&](size_t bytes) { void* p = ws + off; off += (bytes + 255) & ~255ULL; return p; };
  u16* xpw_bf = (u16*)alloc((size_t)64 * DI_ * 2);
  u16* xz     = (u16*)alloc((size_t)NTOK * 2 * DI_ * 2);    // 16.78 MB
  u16* xc     = (u16*)alloc((size_t)NTOK * DI_ * 2);        // 8.39 MB
  float* bc   = (float*)alloc((size_t)NTOK * 32 * 4);
  char* regionA = (char*)alloc((size_t)BATCH * NSEG * DI_ * 16 * 4);  // 8.39 MB
  float* Q = (float*)alloc((size_t)BATCH * NSEG * DI_ * 16 * 4);      // 8.39 MB
  u16* xn   = (u16*)regionA;
  float* P  = (float*)regionA;
  u16* yb   = (u16*)regionA;
  // Q region time-multiplexed: in_w_bf (8.39, until gemm1) -> xp_part (4.2, until
  // xp_finish) -> Q/Hin (until pass2) -> out_w_bf (4.19, until gemm2)
  u16* in_w_bf  = (u16*)Q;
  float* xp_part = Q;
  u16* out_w_bf = (u16*)Q;
  float* out_part = (float*)xz;    // 16.78 MB, xz dead after pass2 (gate fused)
  // total ~42.4 MB (same as proven rounds 8-9)

  cvt_kernel<<<(2 * DI_ * DIM_ / 4 + 255) / 256, 256, 0, stream>>>(in_w, in_w_bf,
                                                                   2 * DI_ * DIM_ / 4);
  cvt_pad_kernel<<<128, 256, 0, stream>>>(xproj_w, xpw_bf);
  ln_kernel<<<NTOK, 256, 0, stream>>>(x, norm_w, norm_b, xn);
  // in_proj: 128x128, BK=64, bf16 W, XCD-swizzled -> 512 blocks (2/CU), 16 K-iters
  gemm_bt<128, 128, 64, u16, 0, 1, 1><<<dim3((2 * DI_) / 128, NTOK / 128), 256, 0, stream>>>(
      xn, in_w_bf, xz, nullptr, NTOK, 2 * DI_, DIM_);
  conv_silu_kernel<<<NTOK, 256, 0, stream>>>(xz, conv_w, conv_b, xc);
  // x_proj: split-K=8, BK=32 -> 256 blocks (in_w_bf now dead; xp_part overwrites)
  gemm_bt<64, 64, 32, float, 0, 8><<<dim3(1, NTOK / 64, 8), 256, 0, stream>>>(
      xc, xpw_bf, xp_part, nullptr, NTOK, 64, DI_);
  xp_finish_kernel<<<NTOK, 256, 0, stream>>>(xp_part, dt_w, dt_b, xz, bc);
  scan_pass1<<<dim3(DI_ / 64, NSEG, BATCH), 256, 0, stream>>>(bc, xz, xc, A_log, P, Q);
  scan_combine<<<BATCH * DI_ * 16 / 256, 256, 0, stream>>>(P, Q);
  scan_pass2<<<dim3(DI_ / 64, NSEG, BATCH), 256, 0, stream>>>(bc, xz, xc, A_log, D_skip,
                                                              Q, yb);
  // Hin dead -> convert out_w into Q region
  cvt_kernel<<<(DIM_ * DI_ / 4 + 255) / 256, 256, 0, stream>>>(out_w, out_w_bf,
                                                               DIM_ * DI_ / 4);
  // out_proj: 128x64, BK=64, split-K=2, bf16 W, XCD-swizzled -> 512 blocks (2/CU)
  gemm_bt<128, 64, 64, float, 0, 2, 1><<<dim3(DIM_ / 64, NTOK / 128, 2), 256, 0, stream>>>(
      yb, out_w_bf, out_part, nullptr, NTOK, DIM_, DI_);
  reduce_out_kernel<<<NTOK * DIM_ / 4 / 256, 256, 0, stream>>>(out_part, x, out);
}

// Round 11
// 235.473 us; speedup vs baseline: 1.0285x; 1.0263x over previous
//
#include <hip/hip_runtime.h>
#include <stdint.h>

#define BATCH 2
#define SEQ   1024
#define DIM_  1024
#define DS_   16
#define DI_   2048
#define NTOK  (BATCH*SEQ)   // 2048
#define NSEG  32
#define LSEG  (SEQ/NSEG)    // 32

typedef unsigned short u16;
using s16x8 = __attribute__((ext_vector_type(8))) short;
using f32x4 = __attribute__((ext_vector_type(4))) float;
using u16x4 = __attribute__((ext_vector_type(4))) unsigned short;
using u16x8 = __attribute__((ext_vector_type(8))) unsigned short;

__device__ __forceinline__ float bf2f(u16 u) {
  union { unsigned int i; float f; } c; c.i = ((unsigned int)u) << 16; return c.f;
}
__device__ __forceinline__ u16 f2bf(float f) {
  union { float f; unsigned int i; } c; c.f = f;
  unsigned int r = c.i + 0x7fffu + ((c.i >> 16) & 1u);
  return (u16)(r >> 16);
}
__device__ __forceinline__ float softplus_f(float x) {
  return (x > 15.f) ? x : __logf(1.f + __expf(x));
}
__device__ __forceinline__ u16x4 f4_to_bf(float4 v) {
  u16x4 r; r[0] = f2bf(v.x); r[1] = f2bf(v.y); r[2] = f2bf(v.z); r[3] = f2bf(v.w);
  return r;
}

// ---------------- merged weight conversion: in_w, out_w, x_proj_w(padded) ----------------
#define N4_INW  (2 * DI_ * DIM_ / 4)   // 1048576
#define N4_OUTW (DIM_ * DI_ / 4)       // 524288
__global__ __launch_bounds__(256) void cvt_all_kernel(const float* __restrict__ in_w,
    const float* __restrict__ out_w, const float* __restrict__ xproj_w,
    u16* __restrict__ in_w_bf, u16* __restrict__ out_w_bf, u16* __restrict__ xpw_bf) {
  int i = blockIdx.x * 256 + threadIdx.x;
  if (i < N4_INW) {
    ((u16x4*)in_w_bf)[i] = f4_to_bf(((const float4*)in_w)[i]);
  } else if (i < N4_INW + N4_OUTW) {
    int j = i - N4_INW;
    ((u16x4*)out_w_bf)[j] = f4_to_bf(((const float4*)out_w)[j]);
  } else {
    int j = i - (N4_INW + N4_OUTW);   // 0..32767 over (64,2048)
    if (j >= 32768) return;
    int p = (j * 4) >> 11;
    u16x4 r;
    if (p < 33) r = f4_to_bf(((const float4*)xproj_w)[j]);
    else { r[0] = 0; r[1] = 0; r[2] = 0; r[3] = 0; }
    ((u16x4*)xpw_bf)[j] = r;
  }
}

// ---------------- LayerNorm ----------------
__global__ __launch_bounds__(256) void ln_kernel(const float* __restrict__ x,
    const float* __restrict__ w, const float* __restrict__ b, u16* __restrict__ xn) {
  int t = blockIdx.x, tid = threadIdx.x;
  const float* row = x + (size_t)t * DIM_;
  float4 v = ((const float4*)row)[tid];
  float f[4] = {v.x, v.y, v.z, v.w};
  float s = 0.f, sq = 0.f;
#pragma unroll
  for (int j = 0; j < 4; j++) { s += f[j]; sq += f[j] * f[j]; }
#pragma unroll
  for (int m = 1; m < 64; m <<= 1) { s += __shfl_xor(s, m); sq += __shfl_xor(sq, m); }
  __shared__ float rs_[4], rq_[4];
  int wv = tid >> 6;
  if ((tid & 63) == 0) { rs_[wv] = s; rq_[wv] = sq; }
  __syncthreads();
  s = rs_[0] + rs_[1] + rs_[2] + rs_[3];
  sq = rq_[0] + rq_[1] + rq_[2] + rq_[3];
  float mu = s * (1.0f / DIM_);
  float var = sq * (1.0f / DIM_) - mu * mu;
  float rstd = rsqrtf(var + 1e-5f);
  float4 wn = ((const float4*)w)[tid];
  float4 bn = ((const float4*)b)[tid];
  u16x4 o;
  o[0] = f2bf((f[0] - mu) * rstd * wn.x + bn.x);
  o[1] = f2bf((f[1] - mu) * rstd * wn.y + bn.y);
  o[2] = f2bf((f[2] - mu) * rstd * wn.z + bn.z);
  o[3] = f2bf((f[3] - mu) * rstd * wn.w + bn.w);
  *(u16x4*)(xn + (size_t)t * DIM_ + tid * 4) = o;
}

// ---------------- GEMM C = A(M,K)bf16 * W(N,K)^T bf16, f32 acc ----------------
template<int TBM, int TBN, int BK, typename OUT, int EPI, int KSPLIT = 1, int SWZ = 0>
__global__ __launch_bounds__(256) void gemm_bt(const u16* __restrict__ A,
    const u16* __restrict__ Wt, OUT* __restrict__ C, const float* __restrict__ X,
    int M, int N, int K) {
  constexpr int LDT = BK + 8;
  constexpr int TPR = BK / 8;
  constexpr int RPP = 256 / TPR;
  constexpr int ALn = TBM / RPP;
  constexpr int BLn = TBN / RPP;
  constexpr int KK = BK / 32;
  constexpr int WM = TBM / 2, WN = TBN / 2;
  constexpr int MI = WM / 16, NJ = WN / 16;
  __shared__ __align__(16) u16 sA[TBM * LDT];
  __shared__ __align__(16) u16 sB[TBN * LDT];
  const int tid = threadIdx.x;
  const int lane = tid & 63, wv = tid >> 6;
  const int wm = (wv >> 1) * WM, wn = (wv & 1) * WN;
  const int bxl = SWZ ? ((blockIdx.x & 7) * (gridDim.x >> 3) + (blockIdx.x >> 3))
                      : blockIdx.x;
  const int bm0 = blockIdx.y * TBM, bn0 = bxl * TBN;
  const int q = lane >> 4, r16 = lane & 15;
  const int srow = tid / TPR, scol = (tid % TPR) * 8;
  const int kc = K / KSPLIT;
  const int k0 = (KSPLIT > 1) ? blockIdx.z * kc : 0;
  const int kend = k0 + kc;

  f32x4 acc[MI][NJ];
#pragma unroll
  for (int i = 0; i < MI; i++)
#pragma unroll
    for (int j = 0; j < NJ; j++)
#pragma unroll
      for (int r = 0; r < 4; r++) acc[i][j][r] = 0.f;

  const u16* Ag = A + (size_t)bm0 * K + scol + k0;
  const u16* Wg = Wt + (size_t)bn0 * K + scol + k0;
  s16x8 ra[ALn], rb[BLn];
#pragma unroll
  for (int i = 0; i < ALn; i++) ra[i] = *(const s16x8*)(Ag + (size_t)(srow + i * RPP) * K);
#pragma unroll
  for (int i = 0; i < BLn; i++) rb[i] = *(const s16x8*)(Wg + (size_t)(srow + i * RPP) * K);

  for (int kt = k0; kt < kend; kt += BK) {
    __syncthreads();
#pragma unroll
    for (int i = 0; i < ALn; i++) *(s16x8*)&sA[(srow + i * RPP) * LDT + scol] = ra[i];
#pragma unroll
    for (int i = 0; i < BLn; i++) *(s16x8*)&sB[(srow + i * RPP) * LDT + scol] = rb[i];
    __syncthreads();
    int kn = kt + BK - k0;
    if (kn < kc) {
#pragma unroll
      for (int i = 0; i < ALn; i++) ra[i] = *(const s16x8*)(Ag + (size_t)(srow + i * RPP) * K + kn);
#pragma unroll
      for (int i = 0; i < BLn; i++) rb[i] = *(const s16x8*)(Wg + (size_t)(srow + i * RPP) * K + kn);
    }
#pragma unroll
    for (int kk = 0; kk < KK; kk++) {
      s16x8 fa[MI], fb[NJ];
#pragma unroll
      for (int i = 0; i < MI; i++)
        fa[i] = *(const s16x8*)&sA[(wm + i * 16 + r16) * LDT + kk * 32 + q * 8];
#pragma unroll
      for (int j = 0; j < NJ; j++)
        fb[j] = *(const s16x8*)&sB[(wn + j * 16 + r16) * LDT + kk * 32 + q * 8];
#pragma unroll
      for (int i = 0; i < MI; i++)
#pragma unroll
        for (int j = 0; j < NJ; j++)
          acc[i][j] = __builtin_amdgcn_mfma_f32_16x16x32_bf16(fa[i], fb[j], acc[i][j], 0, 0, 0);
    }
  }
  OUT* Cz = C + ((KSPLIT > 1) ? (size_t)blockIdx.z * M * N : 0);
#pragma unroll
  for (int i = 0; i < MI; i++)
#pragma unroll
    for (int j = 0; j < NJ; j++) {
      int row0 = bm0 + wm + i * 16 + q * 4;
      int col = bn0 + wn + j * 16 + r16;
#pragma unroll
      for (int r = 0; r < 4; r++) {
        size_t off = (size_t)(row0 + r) * N + col;
        float v = acc[i][j][r];
        if constexpr (EPI == 1) v += X[off];
        if constexpr (sizeof(OUT) == 2) Cz[off] = f2bf(v);
        else                            Cz[off] = v;
      }
    }
}

// ---------------- depthwise causal conv (DC=4) + silu ----------------
__global__ __launch_bounds__(256) void conv_silu_kernel(const u16* __restrict__ xz,
    const float* __restrict__ cw, const float* __restrict__ cb, u16* __restrict__ xc) {
  int t = blockIdx.x;
  int l = t & (SEQ - 1);
  int c0 = threadIdx.x * 8;
  float acc[8], wk[8][4];
#pragma unroll
  for (int j = 0; j < 8; j++) {
    float4 wv = ((const float4*)cw)[c0 + j];
    wk[j][0] = wv.x; wk[j][1] = wv.y; wk[j][2] = wv.z; wk[j][3] = wv.w;
    acc[j] = cb[c0 + j];
  }
#pragma unroll
  for (int k = 0; k < 4; k++) {
    int lk = l - 3 + k;
    if (lk >= 0) {
      u16x8 v = *(const u16x8*)(xz + (size_t)(t - 3 + k) * (2 * DI_) + c0);
#pragma unroll
      for (int j = 0; j < 8; j++) acc[j] = fmaf(bf2f(v[j]), wk[j][k], acc[j]);
    }
  }
  u16x8 o;
#pragma unroll
  for (int j = 0; j < 8; j++) {
    float a = acc[j];
    o[j] = f2bf(a / (1.0f + __expf(-a)));
  }
  *(u16x8*)(xc + (size_t)t * DI_ + c0) = o;
}

// ---------------- fused: split-K reduce of xproj + delta(softplus) + B/C repack ----------------
__global__ __launch_bounds__(256) void xp_finish_kernel(const float* __restrict__ part,
    const float* __restrict__ dtw, const float* __restrict__ dtb,
    u16* __restrict__ xz, float* __restrict__ bc) {
  int t = blockIdx.x;
  int tid = threadIdx.x;
  __shared__ float xps[64];
  if (tid < 64) {
    float s = 0.f;
#pragma unroll
    for (int k = 0; k < 8; k++)
      s += part[(size_t)k * NTOK * 64 + (size_t)t * 64 + tid];
    xps[tid] = s;
  }
  __syncthreads();
  if (tid < 32) bc[(size_t)t * 32 + tid] = xps[1 + tid];
  float dr = xps[0];
  int c0 = tid * 8;
  float wv[8], bv[8];
  *(float4*)wv = ((const float4*)(dtw + c0))[0];
  *(float4*)(wv + 4) = ((const float4*)(dtw + c0))[1];
  *(float4*)bv = ((const float4*)(dtb + c0))[0];
  *(float4*)(bv + 4) = ((const float4*)(dtb + c0))[1];
  u16x8 o;
#pragma unroll
  for (int j = 0; j < 8; j++) o[j] = f2bf(softplus_f(dr * wv[j] + bv[j]));
  *(u16x8*)(xz + (size_t)t * (2 * DI_) + c0) = o;
}

// ============ segmented selective scan (4 states/lane) ============
__global__ __launch_bounds__(256) void scan_pass1(const float* __restrict__ bc,
    const u16* __restrict__ dlt, const u16* __restrict__ xc,
    const float* __restrict__ A_log, float* __restrict__ P, float* __restrict__ Q) {
  int tid = threadIdx.x;
  int lane = tid & 63, wv = tid >> 6;
  int nl = (lane & 3) * 4;
  int d = blockIdx.x * 64 + wv * 16 + (lane >> 2);
  int s = blockIdx.y, b = blockIdx.z;
  int t0 = b * SEQ + s * LSEG;
  float4 Ain = *(const float4*)(A_log + d * DS_ + nl);
  f32x4 Av;
  Av[0] = -__expf(Ain.x); Av[1] = -__expf(Ain.y);
  Av[2] = -__expf(Ain.z); Av[3] = -__expf(Ain.w);
  f32x4 Pv, h;
#pragma unroll
  for (int i = 0; i < 4; i++) { Pv[i] = 1.f; h[i] = 0.f; }
#pragma unroll 8
  for (int j = 0; j < LSEG; j++) {
    int t = t0 + j;
    float delta = bf2f(dlt[(size_t)t * (2 * DI_) + d]);
    float xcv = bf2f(xc[(size_t)t * DI_ + d]);
    float4 B4 = *(const float4*)(bc + (size_t)t * 32 + nl);
    float du = delta * xcv;
#pragma unroll
    for (int i = 0; i < 4; i++) {
      float a = __expf(delta * Av[i]);
      Pv[i] *= a;
      float bi = (i == 0) ? B4.x : (i == 1) ? B4.y : (i == 2) ? B4.z : B4.w;
      h[i] = fmaf(a, h[i], du * bi);
    }
  }
  size_t idx = ((size_t)((b * NSEG + s) * DI_ + d)) * 16 + nl;
  *(f32x4*)(P + idx) = Pv;
  *(f32x4*)(Q + idx) = h;
}

__global__ __launch_bounds__(256) void scan_combine(const float* __restrict__ P,
    float* __restrict__ Q) {
  int g = blockIdx.x * 256 + threadIdx.x;
  int n = g & 15, d = (g >> 4) & (DI_ - 1), b = g >> 15;
  size_t base = ((size_t)b * NSEG * DI_ + d) * 16 + n;
  constexpr size_t STR = (size_t)DI_ * 16;
  float p_[NSEG], q_[NSEG];
#pragma unroll
  for (int s = 0; s < NSEG; s++) {
    p_[s] = P[base + s * STR];
    q_[s] = Q[base + s * STR];
  }
  float hh = 0.f;
#pragma unroll
  for (int s = 0; s < NSEG; s++) {
    Q[base + s * STR] = hh;
    hh = fmaf(p_[s], hh, q_[s]);
  }
}

// pass2 + fused gate: y = (p + xc*D) * silu(z)
__global__ __launch_bounds__(256) void scan_pass2(const float* __restrict__ bc,
    const u16* __restrict__ dlt, const u16* __restrict__ xc,
    const float* __restrict__ A_log, const float* __restrict__ Dskip,
    const float* __restrict__ Hin, u16* __restrict__ yb) {
  int tid = threadIdx.x;
  int lane = tid & 63, wv = tid >> 6;
  int nl = (lane & 3) * 4;
  int d = blockIdx.x * 64 + wv * 16 + (lane >> 2);
  int s = blockIdx.y, b = blockIdx.z;
  int t0 = b * SEQ + s * LSEG;
  float4 Ain = *(const float4*)(A_log + d * DS_ + nl);
  f32x4 Av;
  Av[0] = -__expf(Ain.x); Av[1] = -__expf(Ain.y);
  Av[2] = -__expf(Ain.z); Av[3] = -__expf(Ain.w);
  float Dv = Dskip[d];
  size_t idx = ((size_t)((b * NSEG + s) * DI_ + d)) * 16 + nl;
  f32x4 h = *(const f32x4*)(Hin + idx);
#pragma unroll 8
  for (int j = 0; j < LSEG; j++) {
    int t = t0 + j;
    float delta = bf2f(dlt[(size_t)t * (2 * DI_) + d]);
    float xcv = bf2f(xc[(size_t)t * DI_ + d]);
    float4 B4 = *(const float4*)(bc + (size_t)t * 32 + nl);
    float4 C4 = *(const float4*)(bc + (size_t)t * 32 + 16 + nl);
    float du = delta * xcv;
#pragma unroll
    for (int i = 0; i < 4; i++) {
      float a = __expf(delta * Av[i]);
      float bi = (i == 0) ? B4.x : (i == 1) ? B4.y : (i == 2) ? B4.z : B4.w;
      h[i] = fmaf(a, h[i], du * bi);
    }
    float p = h[0] * C4.x;
    p = fmaf(h[1], C4.y, p);
    p = fmaf(h[2], C4.z, p);
    p = fmaf(h[3], C4.w, p);
    p += __shfl_xor(p, 1);
    p += __shfl_xor(p, 2);
    if ((lane & 3) == 0) {
      float z = bf2f(dlt[(size_t)t * (2 * DI_) + DI_ + d]);
      float sz = z / (1.0f + __expf(-z));
      yb[(size_t)t * DI_ + d] = f2bf((p + xcv * Dv) * sz);
    }
  }
}

extern "C" void kernel_launch(void* const* d_in, const int* in_sizes, int n_in,
                              void* d_out, int out_size, void* d_ws, size_t ws_size,
                              hipStream_t stream) {
  const float* x      = (const float*)d_in[0];
  const float* norm_w = (const float*)d_in[1];
  const float* norm_b = (const float*)d_in[2];
  const float* in_w   = (const float*)d_in[3];
  const float* conv_w = (const float*)d_in[4];
  const float* conv_b = (const float*)d_in[5];
  const float* xproj_w= (const float*)d_in[6];
  const float* dt_w   = (const float*)d_in[7];
  const float* dt_b   = (const float*)d_in[8];
  const float* A_log  = (const float*)d_in[9];
  const float* D_skip = (const float*)d_in[10];
  const float* out_w  = (const float*)d_in[11];
  float* out = (float*)d_out;

  // ws_size = 256 MiB (measured: harness poison fill WRITE_SIZE = 262144 KB).
  // Dedicated buffers, no aliasing (~62 MB total).
  char* ws = (char*)d_ws;
  size_t off = 0;
  auto alloc = [&](size_t bytes) { void* p = ws + off; off += (bytes + 255) & ~255ULL; return p; };
  u16* in_w_bf  = (u16*)alloc((size_t)2 * DI_ * DIM_ * 2);   // 8.39 MB
  u16* out_w_bf = (u16*)alloc((size_t)DIM_ * DI_ * 2);       // 4.19 MB
  u16* xpw_bf   = (u16*)alloc((size_t)64 * DI_ * 2);         // 0.26 MB
  u16* xn       = (u16*)alloc((size_t)NTOK * DIM_ * 2);      // 4.19 MB
  u16* xz       = (u16*)alloc((size_t)NTOK * 2 * DI_ * 2);   // 16.78 MB
  u16* xc       = (u16*)alloc((size_t)NTOK * DI_ * 2);       // 8.39 MB
  float* bc     = (float*)alloc((size_t)NTOK * 32 * 4);      // 0.26 MB
  float* xp_part= (float*)alloc((size_t)8 * NTOK * 64 * 4);  // 4.19 MB
  float* P      = (float*)alloc((size_t)BATCH * NSEG * DI_ * 16 * 4);  // 8.39 MB
  float* Q      = (float*)alloc((size_t)BATCH * NSEG * DI_ * 16 * 4);  // 8.39 MB
  u16* yb       = (u16*)alloc((size_t)NTOK * DI_ * 2);       // 8.39 MB

  // 1: all weight conversions in one node
  cvt_all_kernel<<<(N4_INW + N4_OUTW + 32768 + 255) / 256, 256, 0, stream>>>(
      in_w, out_w, xproj_w, in_w_bf, out_w_bf, xpw_bf);
  // 2
  ln_kernel<<<NTOK, 256, 0, stream>>>(x, norm_w, norm_b, xn);
  // 3: in_proj 128x128, BK=64, XCD-swizzled -> 512 blocks (2/CU)
  gemm_bt<128, 128, 64, u16, 0, 1, 1><<<dim3((2 * DI_) / 128, NTOK / 128), 256, 0, stream>>>(
      xn, in_w_bf, xz, nullptr, NTOK, 2 * DI_, DIM_);
  // 4
  conv_silu_kernel<<<NTOK, 256, 0, stream>>>(xz, conv_w, conv_b, xc);
  // 5: x_proj split-K=8, BK=32 -> 256 blocks
  gemm_bt<64, 64, 32, float, 0, 8><<<dim3(1, NTOK / 64, 8), 256, 0, stream>>>(
      xc, xpw_bf, xp_part, nullptr, NTOK, 64, DI_);
  // 6
  xp_finish_kernel<<<NTOK, 256, 0, stream>>>(xp_part, dt_w, dt_b, xz, bc);
  // 7
  scan_pass1<<<dim3(DI_ / 64, NSEG, BATCH), 256, 0, stream>>>(bc, xz, xc, A_log, P, Q);
  // 8
  scan_combine<<<BATCH * DI_ * 16 / 256, 256, 0, stream>>>(P, Q);
  // 9
  scan_pass2<<<dim3(DI_ / 64, NSEG, BATCH), 256, 0, stream>>>(bc, xz, xc, A_log, D_skip,
                                                              Q, yb);
  // 10: out_proj 64x64, BK=64, EPI=1 direct (no split-K, no reduce) -> 512 blocks (2/CU)
  gemm_bt<64, 64, 64, float, 1, 1, 1><<<dim3(DIM_ / 64, NTOK / 64), 256, 0, stream>>>(
      yb, out_w_bf, out, x, NTOK, DIM_, DI_);
}